// Round 3
// baseline (279.667 us; speedup 1.0000x reference)
//
#include <hip/hip_runtime.h>
#include <math.h>

// ---------------------------------------------------------------------------
// LSGC: B=32, C=128, H=W=64. N_pixels = 32*64*64 = 131072.
// All intermediates stored as bf16 "k-pair" dwords: d = bf16[2c] | bf16[2c+1]<<16,
// layout [b][c/2][hw] — exactly MFMA B-frag pair order, so GEMM staging is a
// raw 16B copy and B-frags are 4 strided ds_read_b32 (conflict-free).
//   1) stencil: fmax = x - min(...); emits x-pairs and fmax-pairs (+w prep)
//   2) gemm1 dual: y_in = w_in @ x ; y_df = w_diff @ fmax  (+BN partial stats)
//   3) reduce + finalize1: BN scales; w_eff = w_mr * col-scale
//   4) gemm2: h = w_eff @ [y_in ; y_df] (+BN partial stats)
//   5) reduce + finalize2 ; 6) epilogue: out = a_in*y_in + d_in + gelu(a_m*h + d_m)
// GEMM C-write: per-wave LDS transpose (own buffer, no barrier) -> full-line
// NONTEMPORAL stores. WRITE_SIZE showed 1.9x amplification on the cached write
// path regardless of store pattern; nt-stores take the single-write path and
// avoid L2 pollution. Epilogue fp32 output (never re-read) also nt.
// A-side (weights) kept hi/lo split (2 mfma: ah*b + al*b) for fp32-grade w.
// ---------------------------------------------------------------------------

#define INV_NPIX (1.0f / 131072.0f)
#define EPS 1e-5f
#define KP 66   // LDS dword pitch per k2-row for B staging (64 + 2)
#define TP 68   // LDS dword pitch for C transpose (64 + 4: keeps 16B align)

typedef __attribute__((ext_vector_type(8))) short s16x8;
typedef __attribute__((ext_vector_type(4))) float f32x4;
typedef __attribute__((ext_vector_type(4))) uint32_t u32x4;

__device__ __forceinline__ uint32_t bf16_rne(float v) {
  uint32_t x = __float_as_uint(v);
  return (x + 0x7fffu + ((x >> 16) & 1u)) >> 16;
}
// pack (hi bf16) | (lo bf16 << 16), v ~= hi + lo   (A-side hi/lo split)
__device__ __forceinline__ uint32_t pack_hl(float v) {
  uint32_t h = bf16_rne(v);
  float lo = v - __uint_as_float(h << 16);
  return h | (bf16_rne(lo) << 16);
}
__device__ __forceinline__ float bf_lo(uint32_t d) {
  return __uint_as_float(d << 16);
}
__device__ __forceinline__ float bf_hi(uint32_t d) {
  return __uint_as_float(d & 0xffff0000u);
}
__device__ __forceinline__ float4 fmin4(float4 a, float4 b) {
  return make_float4(fminf(a.x, b.x), fminf(a.y, b.y), fminf(a.z, b.z),
                     fminf(a.w, b.w));
}

// ------------- stencil (2 planes/block) + pair-pack + prep ------------------
// blocks 0..2047: (b, cpair) planes -> x-pairs + fmax-pairs.
// blocks 2048..2175: weight frag-pack.
__global__ __launch_bounds__(256) void stencil_prep_kernel(
    const float* __restrict__ x, uint32_t* __restrict__ xp,
    uint32_t* __restrict__ fp, const float* __restrict__ w_in,
    const float* __restrict__ w_diff, unsigned short* __restrict__ wInH,
    unsigned short* __restrict__ wInL, unsigned short* __restrict__ wDfH,
    unsigned short* __restrict__ wDfL) {
  __shared__ float4 pA[1024];
  __shared__ float4 pB[1024];
  if (blockIdx.x >= 2048) {
    const int t = (blockIdx.x - 2048) * 256 + threadIdx.x;  // 0..32767
    const int e = t & 16383;
    const float* w = (t < 16384) ? w_in : w_diff;
    unsigned short* aH = (t < 16384) ? wInH : wDfH;
    unsigned short* aL = (t < 16384) ? wInL : wDfL;
    const int j = e & 7, l = (e >> 3) & 63, mt = (e >> 9) & 7, kc = e >> 12;
    const int m = mt * 16 + (l & 15);
    const int k = kc * 32 + ((l >> 4) << 3) + j;
    const uint32_t p = pack_hl(w[m * 128 + k]);
    aH[e] = (unsigned short)(p & 0xffffu);
    aL[e] = (unsigned short)(p >> 16);
    return;
  }
  const int b = blockIdx.x >> 6;
  const int cp = blockIdx.x & 63;
  const float4* xa = (const float4*)x + (size_t)(b * 128 + 2 * cp) * 1024;
  const float4* xb = xa + 1024;
  float4 sA[4], sB[4];
#pragma unroll
  for (int i = 0; i < 4; ++i) {
    const int u = threadIdx.x + i * 256;
    sA[i] = xa[u];
    sB[i] = xb[u];
    pA[u] = sA[i];
    pB[u] = sB[i];
  }
  __syncthreads();
  const size_t obase = (size_t)(b * 64 + cp) * 1024;  // uint4 units
#pragma unroll
  for (int i = 0; i < 4; ++i) {
    const int u = threadIdx.x + i * 256;
    const int h = u >> 4, wu = u & 15;
    const int row = u & ~15;
    float4 mA, mB;
    {
      const float4 A = sA[i];
      const float4 L = pA[row | ((wu + 15) & 15)];
      const float4 R = pA[row | ((wu + 1) & 15)];
      float4 m = fmin4(A, fmin4(L, R));
      m = fmin4(m, make_float4(A.z, A.w, R.x, R.y));
      m = fmin4(m, make_float4(L.z, L.w, A.x, A.y));
      m = fmin4(m, pA[row | ((wu + 2) & 15)]);
      m = fmin4(m, pA[row | ((wu + 14) & 15)]);
      m = fmin4(m, pA[row | ((wu + 4) & 15)]);
      m = fmin4(m, pA[row | ((wu + 12) & 15)]);
      m = fmin4(m, pA[row | ((wu + 8) & 15)]);
      m = fmin4(m, pA[(((h + 2) & 63) << 4) | wu]);
      m = fmin4(m, pA[(((h + 62) & 63) << 4) | wu]);
      m = fmin4(m, pA[(((h + 4) & 63) << 4) | wu]);
      m = fmin4(m, pA[(((h + 60) & 63) << 4) | wu]);
      m = fmin4(m, pA[(((h + 8) & 63) << 4) | wu]);
      m = fmin4(m, pA[(((h + 56) & 63) << 4) | wu]);
      m = fmin4(m, pA[(((h + 16) & 63) << 4) | wu]);
      m = fmin4(m, pA[(((h + 48) & 63) << 4) | wu]);
      m = fmin4(m, pA[(((h + 32) & 63) << 4) | wu]);
      mA = m;
    }
    {
      const float4 A = sB[i];
      const float4 L = pB[row | ((wu + 15) & 15)];
      const float4 R = pB[row | ((wu + 1) & 15)];
      float4 m = fmin4(A, fmin4(L, R));
      m = fmin4(m, make_float4(A.z, A.w, R.x, R.y));
      m = fmin4(m, make_float4(L.z, L.w, A.x, A.y));
      m = fmin4(m, pB[row | ((wu + 2) & 15)]);
      m = fmin4(m, pB[row | ((wu + 14) & 15)]);
      m = fmin4(m, pB[row | ((wu + 4) & 15)]);
      m = fmin4(m, pB[row | ((wu + 12) & 15)]);
      m = fmin4(m, pB[row | ((wu + 8) & 15)]);
      m = fmin4(m, pB[(((h + 2) & 63) << 4) | wu]);
      m = fmin4(m, pB[(((h + 62) & 63) << 4) | wu]);
      m = fmin4(m, pB[(((h + 4) & 63) << 4) | wu]);
      m = fmin4(m, pB[(((h + 60) & 63) << 4) | wu]);
      m = fmin4(m, pB[(((h + 8) & 63) << 4) | wu]);
      m = fmin4(m, pB[(((h + 56) & 63) << 4) | wu]);
      m = fmin4(m, pB[(((h + 16) & 63) << 4) | wu]);
      m = fmin4(m, pB[(((h + 48) & 63) << 4) | wu]);
      m = fmin4(m, pB[(((h + 32) & 63) << 4) | wu]);
      mB = m;
    }
    uint4 px, pf;
    px.x = bf16_rne(sA[i].x) | (bf16_rne(sB[i].x) << 16);
    px.y = bf16_rne(sA[i].y) | (bf16_rne(sB[i].y) << 16);
    px.z = bf16_rne(sA[i].z) | (bf16_rne(sB[i].z) << 16);
    px.w = bf16_rne(sA[i].w) | (bf16_rne(sB[i].w) << 16);
    pf.x = bf16_rne(sA[i].x - mA.x) | (bf16_rne(sB[i].x - mB.x) << 16);
    pf.y = bf16_rne(sA[i].y - mA.y) | (bf16_rne(sB[i].y - mB.y) << 16);
    pf.z = bf16_rne(sA[i].z - mA.z) | (bf16_rne(sB[i].z - mB.z) << 16);
    pf.w = bf16_rne(sA[i].w - mA.w) | (bf16_rne(sB[i].w - mB.w) << 16);
    ((uint4*)xp)[obase + u] = px;
    ((uint4*)fp)[obase + u] = pf;
  }
}

// --------------------------- MFMA GEMM body ---------------------------------
// out[m,n] = sum_k A[m,k]*B[k,n]; M=128, N=131072. B in bf16-pair dwords
// [b][k2][hw]; k2<64 from B0, else B1. Tile M=128 x N=64, k-chunk 32 (16 k2
// rows), ALL B-tiles loaded in prologue (counted-vmcnt drain per chunk),
// A-frags double-buffered (issued after the barrier so L2 latency hides under
// MFMA), double-buffered LDS, 1 barrier/chunk.
// C-write: per-wave LDS transpose in its OWN buffer (no barrier) -> full-line
// nontemporal uint4 stores. Stats: per-block non-atomic partial row [bx][128].
template <int NC>  // 4 (K=128) or 8 (K=256)
__device__ __forceinline__ void gemm_body(
    const unsigned short* __restrict__ AH, const unsigned short* __restrict__ AL,
    const uint32_t* __restrict__ B0, const uint32_t* __restrict__ B1,
    uint32_t* __restrict__ outp, float* __restrict__ pS,
    float* __restrict__ pQ, const int bx, uint32_t* Bs, uint32_t* Ts) {
  const int tid = threadIdx.x;
  const int lane = tid & 63;
  const int wave = tid >> 6;
  const int b = bx >> 6;
  const int hw0 = (bx & 63) << 6;
  const int sk2 = tid >> 4;         // staging k2-row 0..15
  const int sn4 = (tid & 15) << 2;  // staging dword4 column
  const int q = lane >> 4;
  const int ln = lane & 15;

  f32x4 acc[2][4];
#pragma unroll
  for (int i = 0; i < 2; ++i)
#pragma unroll
    for (int j = 0; j < 4; ++j) acc[i][j] = (f32x4)(0.0f);

  // prologue: ALL B-tiles (B0 rows 0..63, then B1 rows 0..63 for NC=8)
  uint4 ld[NC];
#pragma unroll
  for (int c = 0; c < NC; ++c) {
    const uint32_t* src = (c < 4) ? B0 : B1;
    ld[c] = *(const uint4*)&src[((size_t)(b * 64 + (c & 3) * 16 + sk2)) * 4096 +
                                hw0 + sn4];
  }
  // A frags for chunk 0 (L2-resident)
  s16x8 ah[2][2], al[2][2];
#pragma unroll
  for (int mt2 = 0; mt2 < 2; ++mt2) {
    const size_t off = ((size_t)((wave * 2 + mt2) * 64 + lane)) << 3;
    ah[0][mt2] = *(const s16x8*)(AH + off);
    al[0][mt2] = *(const s16x8*)(AL + off);
  }

#pragma unroll
  for (int kc = 0; kc < NC; ++kc) {
    const int cur = kc & 1;
    const int nxt = cur ^ 1;
    uint32_t* buf = Bs + cur * (16 * KP);
    *(uint4*)&buf[sk2 * KP + sn4] = ld[kc];
    __syncthreads();
    // prefetch next chunk's A frags AFTER the barrier: latency hides under
    // this chunk's LDS reads + MFMA instead of being drained by the barrier.
    if (kc + 1 < NC) {
#pragma unroll
      for (int mt2 = 0; mt2 < 2; ++mt2) {
        const size_t off =
            ((size_t)(((kc + 1) * 8 + wave * 2 + mt2) * 64 + lane)) << 3;
        ah[nxt][mt2] = *(const s16x8*)(AH + off);
        al[nxt][mt2] = *(const s16x8*)(AL + off);
      }
    }
#pragma unroll
    for (int nt = 0; nt < 4; ++nt) {
      union { uint32_t u[4]; s16x8 s; } bb;
#pragma unroll
      for (int j = 0; j < 4; ++j)
        bb.u[j] = buf[(q * 4 + j) * KP + nt * 16 + ln];
#pragma unroll
      for (int mt2 = 0; mt2 < 2; ++mt2) {
        acc[mt2][nt] = __builtin_amdgcn_mfma_f32_16x16x32_bf16(
            ah[cur][mt2], bb.s, acc[mt2][nt], 0, 0, 0);
        acc[mt2][nt] = __builtin_amdgcn_mfma_f32_16x16x32_bf16(
            al[cur][mt2], bb.s, acc[mt2][nt], 0, 0, 0);
      }
    }
  }

  // ---- C-write: per-wave LDS transpose (own buffer, no barrier needed) ----
  uint32_t* tb = Ts + wave * (16 * TP);
#pragma unroll
  for (int mt2 = 0; mt2 < 2; ++mt2)
#pragma unroll
    for (int nt = 0; nt < 4; ++nt)
#pragma unroll
      for (int rp = 0; rp < 2; ++rp) {
        const int r = mt2 * 8 + q * 2 + rp;
        tb[r * TP + nt * 16 + ln] = bf16_rne(acc[mt2][nt][2 * rp]) |
                                    (bf16_rne(acc[mt2][nt][2 * rp + 1]) << 16);
      }
  // per-channel partial stats (overlaps LDS write->read latency)
#pragma unroll
  for (int mt2 = 0; mt2 < 2; ++mt2) {
    float sa[4] = {0.f, 0.f, 0.f, 0.f};
    float sq[4] = {0.f, 0.f, 0.f, 0.f};
#pragma unroll
    for (int nt = 0; nt < 4; ++nt) {
#pragma unroll
      for (int rp = 0; rp < 2; ++rp) {
        const float v0 = acc[mt2][nt][2 * rp];
        const float v1 = acc[mt2][nt][2 * rp + 1];
        sa[2 * rp] += v0;
        sq[2 * rp] += v0 * v0;
        sa[2 * rp + 1] += v1;
        sq[2 * rp + 1] += v1 * v1;
      }
    }
#pragma unroll
    for (int off = 1; off < 16; off <<= 1) {
#pragma unroll
      for (int r = 0; r < 4; ++r) {
        sa[r] += __shfl_xor(sa[r], off);
        sq[r] += __shfl_xor(sq[r], off);
      }
    }
    if (ln == 0) {
#pragma unroll
      for (int r = 0; r < 4; ++r) {
        const int m = (wave * 2 + mt2) * 16 + q * 4 + r;
        pS[bx * 128 + m] = sa[r];
        pQ[bx * 128 + m] = sq[r];
      }
    }
  }
  // read back + nontemporal store: pass p covers rows p*4 + (lane>>4);
  // 16 lanes/row = 256B contiguous per row (whole 128B lines, single path).
  const int rr = lane >> 4;
  const int cc = ln << 2;
#pragma unroll
  for (int p = 0; p < 4; ++p) {
    const int r = p * 4 + rr;
    const u32x4 v = *(const u32x4*)&tb[r * TP + cc];
    __builtin_nontemporal_store(
        v, (u32x4*)&outp[((size_t)(b * 64 + wave * 16 + r)) * 4096 + hw0 + cc]);
  }
}

// gemm1a + gemm1b in one dispatch (4096 blocks)
__global__ __launch_bounds__(256) void gemm1_dual(
    const unsigned short* __restrict__ AH1, const unsigned short* __restrict__ AL1,
    const uint32_t* __restrict__ XP, uint32_t* __restrict__ out1,
    float* __restrict__ sv1, float* __restrict__ sq1,
    const unsigned short* __restrict__ AH2, const unsigned short* __restrict__ AL2,
    const uint32_t* __restrict__ FP, uint32_t* __restrict__ out2,
    float* __restrict__ sv2, float* __restrict__ sq2) {
  __shared__ uint32_t Bs[2 * 16 * KP];
  __shared__ uint32_t Ts[4 * 16 * TP];
  const int bx = blockIdx.x & 2047;
  if ((blockIdx.x >> 11) == 0)
    gemm_body<4>(AH1, AL1, XP, nullptr, out1, sv1, sq1, bx, Bs, Ts);
  else
    gemm_body<4>(AH2, AL2, FP, nullptr, out2, sv2, sq2, bx, Bs, Ts);
}

__global__ __launch_bounds__(256) void gemm2_kernel(
    const unsigned short* __restrict__ AH, const unsigned short* __restrict__ AL,
    const uint32_t* __restrict__ B0, const uint32_t* __restrict__ B1,
    uint32_t* __restrict__ outp, float* __restrict__ sv,
    float* __restrict__ sq) {
  __shared__ uint32_t Bs[2 * 16 * KP];
  __shared__ uint32_t Ts[4 * 16 * TP];
  gemm_body<8>(AH, AL, B0, B1, outp, sv, sq, blockIdx.x, Bs, Ts);
}

// --------------------------- stats reduce -----------------------------------
// P: [nArrays][2048][128] per-tile partials -> p2: [nArrays][16][128].
// grid = nArrays*16 blocks x 256 thr; block (a,g) reduces 128 tile-rows.
__global__ __launch_bounds__(256) void reduce_kernel(
    const float* __restrict__ P, float* __restrict__ p2) {
  const int a = blockIdx.x >> 4, g = blockIdx.x & 15;
  const int c = threadIdx.x & 127, h = threadIdx.x >> 7;
  const float* src = P + ((size_t)(a * 2048 + g * 128 + h * 64)) * 128 + c;
  float s0 = 0.f, s1 = 0.f, s2 = 0.f, s3 = 0.f;
#pragma unroll
  for (int j = 0; j < 64; j += 4) {
    s0 += src[(j + 0) * 128];
    s1 += src[(j + 1) * 128];
    s2 += src[(j + 2) * 128];
    s3 += src[(j + 3) * 128];
  }
  __shared__ float sm[256];
  sm[threadIdx.x] = (s0 + s1) + (s2 + s3);
  __syncthreads();
  if (h == 0) p2[(a * 16 + g) * 128 + c] = sm[c] + sm[128 + c];
}

// --------------------------- finalize kernels -------------------------------
// p2 layout: [0]=sum_in [1]=sq_in [2]=sum_df [3]=sq_df, each [16][128].
__global__ __launch_bounds__(256) void finalize1_kernel(
    const float* __restrict__ p2, const float* __restrict__ g_ibn,
    const float* __restrict__ be_ibn, const float* __restrict__ g_bn,
    const float* __restrict__ w_mr, float* __restrict__ a_in,
    float* __restrict__ d_in, unsigned short* __restrict__ wEffH,
    unsigned short* __restrict__ wEffL) {
  __shared__ float sa[256];
  const int t = threadIdx.x;
  if (t < 128) {
    float s = 0.f, qq = 0.f;
#pragma unroll
    for (int g = 0; g < 16; ++g) {
      s += p2[g * 128 + t];
      qq += p2[(16 + g) * 128 + t];
    }
    const float mu = s * INV_NPIX;
    const float var = fmaxf(qq * INV_NPIX - mu * mu, 0.f);
    const float a = g_ibn[t] * rsqrtf(var + EPS);
    if (blockIdx.x == 0) {
      a_in[t] = a;
      d_in[t] = be_ibn[t] - mu * a;
    }
    sa[t] = a;
  } else {
    const int c = t - 128;
    float s = 0.f, qq = 0.f;
#pragma unroll
    for (int g = 0; g < 16; ++g) {
      s += p2[(32 + g) * 128 + c];
      qq += p2[(48 + g) * 128 + c];
    }
    const float mu = s * INV_NPIX;
    const float var = fmaxf(qq * INV_NPIX - mu * mu, 0.f);
    sa[t] = g_bn[c] * rsqrtf(var + EPS);
  }
  __syncthreads();
  const int e = blockIdx.x * 256 + t;
  const int j = e & 7, l = (e >> 3) & 63, mt = (e >> 9) & 7, kc = e >> 12;
  const int m = mt * 16 + (l & 15);
  const int k = kc * 32 + ((l >> 4) << 3) + j;
  const uint32_t p = pack_hl(w_mr[m * 256 + k] * sa[k]);
  wEffH[e] = (unsigned short)(p & 0xffffu);
  wEffL[e] = (unsigned short)(p >> 16);
}

// p2h layout: [0]=sum_h [1]=sq_h, each [16][128].
__global__ __launch_bounds__(128) void finalize2_kernel(
    const float* __restrict__ p2h, const float* __restrict__ g_mbn,
    const float* __restrict__ be_mbn, float* __restrict__ a_m,
    float* __restrict__ d_m) {
  const int t = threadIdx.x;
  float s = 0.f, qq = 0.f;
#pragma unroll
  for (int g = 0; g < 16; ++g) {
    s += p2h[g * 128 + t];
    qq += p2h[(16 + g) * 128 + t];
  }
  const float mu = s * INV_NPIX;
  const float var = fmaxf(qq * INV_NPIX - mu * mu, 0.f);
  const float a = g_mbn[t] * rsqrtf(var + EPS);
  a_m[t] = a;
  d_m[t] = be_mbn[t] - mu * a;
}

// --------------------------- epilogue ---------------------------------------
__device__ __forceinline__ float gelu_exact(float z) {
  return 0.5f * z * (1.0f + erff(z * 0.70710678118654752f));
}

__global__ __launch_bounds__(256) void epilogue_kernel(
    const uint32_t* __restrict__ yp, const uint32_t* __restrict__ hp,
    const float* __restrict__ a_in, const float* __restrict__ d_in,
    const float* __restrict__ a_m, const float* __restrict__ d_m,
    float* __restrict__ out) {
  const size_t i = (size_t)blockIdx.x * 256 + threadIdx.x;  // uint4 index
  const int cp = (int)((i >> 10) & 63);
  const int b = (int)(i >> 16);
  const int c0 = 2 * cp, c1 = 2 * cp + 1;
  const uint4 yv = ((const uint4*)yp)[i];
  const uint4 hv = ((const uint4*)hp)[i];
  const float a0 = a_in[c0], d0 = d_in[c0], m0 = a_m[c0], e0 = d_m[c0];
  const float a1 = a_in[c1], d1 = d_in[c1], m1 = a_m[c1], e1 = d_m[c1];
  f32x4 o0, o1;
  o0[0] = fmaf(a0, bf_lo(yv.x), d0) + gelu_exact(fmaf(m0, bf_lo(hv.x), e0));
  o0[1] = fmaf(a0, bf_lo(yv.y), d0) + gelu_exact(fmaf(m0, bf_lo(hv.y), e0));
  o0[2] = fmaf(a0, bf_lo(yv.z), d0) + gelu_exact(fmaf(m0, bf_lo(hv.z), e0));
  o0[3] = fmaf(a0, bf_lo(yv.w), d0) + gelu_exact(fmaf(m0, bf_lo(hv.w), e0));
  o1[0] = fmaf(a1, bf_hi(yv.x), d1) + gelu_exact(fmaf(m1, bf_hi(hv.x), e1));
  o1[1] = fmaf(a1, bf_hi(yv.y), d1) + gelu_exact(fmaf(m1, bf_hi(hv.y), e1));
  o1[2] = fmaf(a1, bf_hi(yv.z), d1) + gelu_exact(fmaf(m1, bf_hi(hv.z), e1));
  o1[3] = fmaf(a1, bf_hi(yv.w), d1) + gelu_exact(fmaf(m1, bf_hi(hv.w), e1));
  const size_t u = i & 1023;  // float4 col within row
  __builtin_nontemporal_store(
      o0, (f32x4*)&out[((size_t)(b * 128 + c0) * 1024 + u) * 4]);
  __builtin_nontemporal_store(
      o1, (f32x4*)&out[((size_t)(b * 128 + c1) * 1024 + u) * 4]);
}

// --------------------------- launch -----------------------------------------
extern "C" void kernel_launch(void* const* d_in, const int* in_sizes, int n_in,
                              void* d_out, int out_size, void* d_ws,
                              size_t ws_size, hipStream_t stream) {
  const float* x = (const float*)d_in[0];
  const float* w_diff = (const float*)d_in[1];
  const float* g_bn = (const float*)d_in[3];
  const float* w_in = (const float*)d_in[5];
  const float* g_ibn = (const float*)d_in[7];
  const float* be_ibn = (const float*)d_in[8];
  const float* w_mr = (const float*)d_in[9];
  const float* g_mbn = (const float*)d_in[11];
  const float* be_mbn = (const float*)d_in[12];
  float* out = (float*)d_out;

  const size_t PD = (size_t)8388608;  // 32*64*4096 pair-dwords per tensor
  uint32_t* ws = (uint32_t*)d_ws;
  uint32_t* xp = ws;             // x bf16-pairs
  uint32_t* fpx = ws + PD;       // fmax bf16-pairs
  uint32_t* ypIn = ws + 2 * PD;  // y_in pairs
  uint32_t* ypDf = ws + 3 * PD;  // y_df pairs
  uint32_t* hp = ws + 4 * PD;    // h pairs
  float* st = (float*)(ws + 5 * PD);
  // small arrays (st region):
  float* p2 = st;               // [4][16][128] = 8192
  float* p2h = st + 8192;       // [2][16][128] = 4096
  float* a_in = st + 12288, *dinc = st + 12416;
  float* a_m = st + 12544, *d_m = st + 12672;
  unsigned short* fr = (unsigned short*)(st + 12800);
  unsigned short* wInH = fr;           // 16384 each
  unsigned short* wInL = fr + 16384;
  unsigned short* wDfH = fr + 32768;
  unsigned short* wDfL = fr + 49152;
  unsigned short* wEffH = fr + 65536;  // 32768 each
  unsigned short* wEffL = fr + 98304;
  // gemm1 per-tile partials live in the (not-yet-written) hp region:
  // [Sin|Qin|Sdf|Qdf] x [2048][128] floats = 4MB; consumed before gemm2 runs.
  float* g1p = (float*)(ws + 4 * PD);
  // gemm2 per-tile partials live in the (already-consumed) xp region:
  float* g2p = (float*)ws;

  stencil_prep_kernel<<<2176, 256, 0, stream>>>(x, xp, fpx, w_in, w_diff,
                                                wInH, wInL, wDfH, wDfL);
  gemm1_dual<<<4096, 256, 0, stream>>>(wInH, wInL, xp, ypIn, g1p,
                                       g1p + 262144, wDfH, wDfL, fpx, ypDf,
                                       g1p + 524288, g1p + 786432);
  reduce_kernel<<<64, 256, 0, stream>>>(g1p, p2);
  finalize1_kernel<<<128, 256, 0, stream>>>(p2, g_ibn, be_ibn, g_bn, w_mr,
                                            a_in, dinc, wEffH, wEffL);
  gemm2_kernel<<<2048, 256, 0, stream>>>(wEffH, wEffL, ypIn, ypDf, hp, g2p,
                                         g2p + 262144);
  reduce_kernel<<<32, 256, 0, stream>>>(g2p, p2h);
  finalize2_kernel<<<1, 128, 0, stream>>>(p2h, g_mbn, be_mbn, a_m, d_m);
  epilogue_kernel<<<8192, 256, 0, stream>>>(ypIn, hp, a_in, dinc, a_m, d_m,
                                            out);
}

// Round 5
// 253.447 us; speedup vs baseline: 1.1035x; 1.1035x over previous
//
#include <hip/hip_runtime.h>
#include <math.h>

// ---------------------------------------------------------------------------
// LSGC: B=32, C=128, H=W=64. N_pixels = 32*64*64 = 131072.
// All intermediates stored as bf16 "k-pair" dwords: d = bf16[2c] | bf16[2c+1]<<16,
// layout [b][c/2][hw] — exactly MFMA B-frag pair order, so GEMM staging is a
// raw 16B copy and B-frags are 4 strided ds_read_b32 (conflict-free).
//   1) stencil: fmax = x - min(...); emits x-pairs and fmax-pairs (+w prep)
//   2) gemm1 dual (persistent, 4 tiles/block): y_in = w_in @ x ; y_df = w_diff @ fmax
//   3) reduce + finalize1: BN scales; w_eff = w_mr * col-scale
//   4) gemm2 (persistent, 2 tiles/block): h = w_eff @ [y_in ; y_df]
//   5) reduce + finalize2 ; 6) epilogue: out = a_in*y_in + d_in + gelu(a_m*h + d_m)
// GEMM structure: full B-tile staged per LDS buffer -> ONE barrier per tile
// (the compiler's vmcnt(0) drain at s_barrier caps prefetch distance at one
// stage; big stages give each drain a full tile of latency budget). Persistent
// blocks amortize the prologue and overlap C-writes with next-tile loads.
// Stats are per-block NON-ATOMIC partial writes (atomics = fabric RMW, r1).
// A-side (weights) kept hi/lo split (2 mfma: ah*b + al*b) for fp32-grade w.
// ---------------------------------------------------------------------------

#define INV_NPIX (1.0f / 131072.0f)
#define EPS 1e-5f
#define KP 66  // LDS dword pitch per k2-row (64 + 2: conflict-free)
#define T1 4   // tiles per block, gemm1
#define T2 2   // tiles per block, gemm2

typedef __attribute__((ext_vector_type(8))) short s16x8;
typedef __attribute__((ext_vector_type(4))) float f32x4;

__device__ __forceinline__ uint32_t bf16_rne(float v) {
  uint32_t x = __float_as_uint(v);
  return (x + 0x7fffu + ((x >> 16) & 1u)) >> 16;
}
// pack (hi bf16) | (lo bf16 << 16), v ~= hi + lo   (A-side hi/lo split)
__device__ __forceinline__ uint32_t pack_hl(float v) {
  uint32_t h = bf16_rne(v);
  float lo = v - __uint_as_float(h << 16);
  return h | (bf16_rne(lo) << 16);
}
__device__ __forceinline__ float bf_lo(uint32_t d) {
  return __uint_as_float(d << 16);
}
__device__ __forceinline__ float bf_hi(uint32_t d) {
  return __uint_as_float(d & 0xffff0000u);
}
__device__ __forceinline__ float4 fmin4(float4 a, float4 b) {
  return make_float4(fminf(a.x, b.x), fminf(a.y, b.y), fminf(a.z, b.z),
                     fminf(a.w, b.w));
}

// ------------- stencil (2 planes/block) + pair-pack + prep ------------------
__global__ __launch_bounds__(256) void stencil_prep_kernel(
    const float* __restrict__ x, uint32_t* __restrict__ xp,
    uint32_t* __restrict__ fp, const float* __restrict__ w_in,
    const float* __restrict__ w_diff, unsigned short* __restrict__ wInH,
    unsigned short* __restrict__ wInL, unsigned short* __restrict__ wDfH,
    unsigned short* __restrict__ wDfL) {
  __shared__ float4 pA[1024];
  __shared__ float4 pB[1024];
  if (blockIdx.x >= 2048) {
    const int t = (blockIdx.x - 2048) * 256 + threadIdx.x;  // 0..32767
    const int e = t & 16383;
    const float* w = (t < 16384) ? w_in : w_diff;
    unsigned short* aH = (t < 16384) ? wInH : wDfH;
    unsigned short* aL = (t < 16384) ? wInL : wDfL;
    const int j = e & 7, l = (e >> 3) & 63, mt = (e >> 9) & 7, kc = e >> 12;
    const int m = mt * 16 + (l & 15);
    const int k = kc * 32 + ((l >> 4) << 3) + j;
    const uint32_t p = pack_hl(w[m * 128 + k]);
    aH[e] = (unsigned short)(p & 0xffffu);
    aL[e] = (unsigned short)(p >> 16);
    return;
  }
  const int b = blockIdx.x >> 6;
  const int cp = blockIdx.x & 63;
  const float4* xa = (const float4*)x + (size_t)(b * 128 + 2 * cp) * 1024;
  const float4* xb = xa + 1024;
  float4 sA[4], sB[4];
#pragma unroll
  for (int i = 0; i < 4; ++i) {
    const int u = threadIdx.x + i * 256;
    sA[i] = xa[u];
    sB[i] = xb[u];
    pA[u] = sA[i];
    pB[u] = sB[i];
  }
  __syncthreads();
  const size_t obase = (size_t)(b * 64 + cp) * 1024;  // uint4 units
#pragma unroll
  for (int i = 0; i < 4; ++i) {
    const int u = threadIdx.x + i * 256;
    const int h = u >> 4, wu = u & 15;
    const int row = u & ~15;
    float4 mA, mB;
    {
      const float4 A = sA[i];
      const float4 L = pA[row | ((wu + 15) & 15)];
      const float4 R = pA[row | ((wu + 1) & 15)];
      float4 m = fmin4(A, fmin4(L, R));
      m = fmin4(m, make_float4(A.z, A.w, R.x, R.y));
      m = fmin4(m, make_float4(L.z, L.w, A.x, A.y));
      m = fmin4(m, pA[row | ((wu + 2) & 15)]);
      m = fmin4(m, pA[row | ((wu + 14) & 15)]);
      m = fmin4(m, pA[row | ((wu + 4) & 15)]);
      m = fmin4(m, pA[row | ((wu + 12) & 15)]);
      m = fmin4(m, pA[row | ((wu + 8) & 15)]);
      m = fmin4(m, pA[(((h + 2) & 63) << 4) | wu]);
      m = fmin4(m, pA[(((h + 62) & 63) << 4) | wu]);
      m = fmin4(m, pA[(((h + 4) & 63) << 4) | wu]);
      m = fmin4(m, pA[(((h + 60) & 63) << 4) | wu]);
      m = fmin4(m, pA[(((h + 8) & 63) << 4) | wu]);
      m = fmin4(m, pA[(((h + 56) & 63) << 4) | wu]);
      m = fmin4(m, pA[(((h + 16) & 63) << 4) | wu]);
      m = fmin4(m, pA[(((h + 48) & 63) << 4) | wu]);
      m = fmin4(m, pA[(((h + 32) & 63) << 4) | wu]);
      mA = m;
    }
    {
      const float4 A = sB[i];
      const float4 L = pB[row | ((wu + 15) & 15)];
      const float4 R = pB[row | ((wu + 1) & 15)];
      float4 m = fmin4(A, fmin4(L, R));
      m = fmin4(m, make_float4(A.z, A.w, R.x, R.y));
      m = fmin4(m, make_float4(L.z, L.w, A.x, A.y));
      m = fmin4(m, pB[row | ((wu + 2) & 15)]);
      m = fmin4(m, pB[row | ((wu + 14) & 15)]);
      m = fmin4(m, pB[row | ((wu + 4) & 15)]);
      m = fmin4(m, pB[row | ((wu + 12) & 15)]);
      m = fmin4(m, pB[row | ((wu + 8) & 15)]);
      m = fmin4(m, pB[(((h + 2) & 63) << 4) | wu]);
      m = fmin4(m, pB[(((h + 62) & 63) << 4) | wu]);
      m = fmin4(m, pB[(((h + 4) & 63) << 4) | wu]);
      m = fmin4(m, pB[(((h + 60) & 63) << 4) | wu]);
      m = fmin4(m, pB[(((h + 8) & 63) << 4) | wu]);
      m = fmin4(m, pB[(((h + 56) & 63) << 4) | wu]);
      m = fmin4(m, pB[(((h + 16) & 63) << 4) | wu]);
      m = fmin4(m, pB[(((h + 48) & 63) << 4) | wu]);
      m = fmin4(m, pB[(((h + 32) & 63) << 4) | wu]);
      mB = m;
    }
    uint4 px, pf;
    px.x = bf16_rne(sA[i].x) | (bf16_rne(sB[i].x) << 16);
    px.y = bf16_rne(sA[i].y) | (bf16_rne(sB[i].y) << 16);
    px.z = bf16_rne(sA[i].z) | (bf16_rne(sB[i].z) << 16);
    px.w = bf16_rne(sA[i].w) | (bf16_rne(sB[i].w) << 16);
    pf.x = bf16_rne(sA[i].x - mA.x) | (bf16_rne(sB[i].x - mB.x) << 16);
    pf.y = bf16_rne(sA[i].y - mA.y) | (bf16_rne(sB[i].y - mB.y) << 16);
    pf.z = bf16_rne(sA[i].z - mA.z) | (bf16_rne(sB[i].z - mB.z) << 16);
    pf.w = bf16_rne(sA[i].w - mA.w) | (bf16_rne(sB[i].w - mB.w) << 16);
    ((uint4*)xp)[obase + u] = px;
    ((uint4*)fp)[obase + u] = pf;
  }
}

// --------------------------- shared GEMM tails -------------------------------
__device__ __forceinline__ void cwrite_stats(
    const f32x4 (&acc)[2][4], uint32_t* __restrict__ outp,
    float* __restrict__ pS, float* __restrict__ pQ, const int bx, const int b,
    const int hw0, const int wave, const int q, const int ln) {
#pragma unroll
  for (int mt2 = 0; mt2 < 2; ++mt2) {
    float sa[4] = {0.f, 0.f, 0.f, 0.f};
    float sq[4] = {0.f, 0.f, 0.f, 0.f};
#pragma unroll
    for (int nt = 0; nt < 4; ++nt) {
#pragma unroll
      for (int rp = 0; rp < 2; ++rp) {
        const float v0 = acc[mt2][nt][2 * rp];
        const float v1 = acc[mt2][nt][2 * rp + 1];
        const int m2 = (wave * 2 + mt2) * 8 + q * 2 + rp;
        outp[((size_t)(b * 64 + m2)) * 4096 + hw0 + nt * 16 + ln] =
            bf16_rne(v0) | (bf16_rne(v1) << 16);
        sa[2 * rp] += v0;
        sq[2 * rp] += v0 * v0;
        sa[2 * rp + 1] += v1;
        sq[2 * rp + 1] += v1 * v1;
      }
    }
#pragma unroll
    for (int off = 1; off < 16; off <<= 1) {
#pragma unroll
      for (int r = 0; r < 4; ++r) {
        sa[r] += __shfl_xor(sa[r], off);
        sq[r] += __shfl_xor(sq[r], off);
      }
    }
    if (ln == 0) {
#pragma unroll
      for (int r = 0; r < 4; ++r) {
        const int m = (wave * 2 + mt2) * 16 + q * 4 + r;
        pS[bx * 128 + m] = sa[r];
        pQ[bx * 128 + m] = sq[r];
      }
    }
  }
}

// --------------------------- gemm1 persistent (K=128) ------------------------
// Per tile: stage full 64-row B tile -> ONE barrier -> reload next tile's B
// (full tile of drain budget) -> 4 k-chunks of MFMA (A-frags double-buffered)
// -> C-write + stats. LDS: 2 x 64 x KP dwords, parity t&1.
template <int T>
__device__ __forceinline__ void gemm1_persist(
    const unsigned short* __restrict__ AH, const unsigned short* __restrict__ AL,
    const uint32_t* __restrict__ B0, uint32_t* __restrict__ outp,
    float* __restrict__ pS, float* __restrict__ pQ, const int p,
    uint32_t* Bs) {
  const int tid = threadIdx.x;
  const int lane = tid & 63;
  const int wave = tid >> 6;
  const int sk2 = tid >> 4;
  const int sn4 = (tid & 15) << 2;
  const int q = lane >> 4;
  const int ln = lane & 15;

  uint4 ld[4];
  {
    const int bx0 = p * T;
    const int b = bx0 >> 6, hw0 = (bx0 & 63) << 6;
#pragma unroll
    for (int c = 0; c < 4; ++c)
      ld[c] = *(const uint4*)&B0[((size_t)(b * 64 + c * 16 + sk2)) * 4096 +
                                 hw0 + sn4];
  }

#pragma unroll
  for (int t = 0; t < T; ++t) {
    const int bx = p * T + t;
    const int b = bx >> 6, hw0 = (bx & 63) << 6;
    uint32_t* buf = Bs + (t & 1) * (64 * KP);

#pragma unroll
    for (int c = 0; c < 4; ++c)
      *(uint4*)&buf[(c * 16 + sk2) * KP + sn4] = ld[c];

    s16x8 ah[2][2], al[2][2];
#pragma unroll
    for (int mt2 = 0; mt2 < 2; ++mt2) {
      const size_t off = ((size_t)((wave * 2 + mt2) * 64 + lane)) << 3;
      ah[0][mt2] = *(const s16x8*)(AH + off);
      al[0][mt2] = *(const s16x8*)(AL + off);
    }
    __syncthreads();

    if (t + 1 < T) {
      const int bn = bx + 1;
      const int b2 = bn >> 6, hw2 = (bn & 63) << 6;
#pragma unroll
      for (int c = 0; c < 4; ++c)
        ld[c] = *(const uint4*)&B0[((size_t)(b2 * 64 + c * 16 + sk2)) * 4096 +
                                   hw2 + sn4];
    }

    f32x4 acc[2][4];
#pragma unroll
    for (int i = 0; i < 2; ++i)
#pragma unroll
      for (int j = 0; j < 4; ++j) acc[i][j] = (f32x4)(0.0f);

#pragma unroll
    for (int kc = 0; kc < 4; ++kc) {
      if (kc < 3) {
#pragma unroll
        for (int mt2 = 0; mt2 < 2; ++mt2) {
          const size_t off =
              ((size_t)(((kc + 1) * 8 + wave * 2 + mt2) * 64 + lane)) << 3;
          ah[(kc + 1) & 1][mt2] = *(const s16x8*)(AH + off);
          al[(kc + 1) & 1][mt2] = *(const s16x8*)(AL + off);
        }
      }
#pragma unroll
      for (int nt = 0; nt < 4; ++nt) {
        union { uint32_t u[4]; s16x8 s; } bb;
#pragma unroll
        for (int j = 0; j < 4; ++j)
          bb.u[j] = buf[(kc * 16 + q * 4 + j) * KP + nt * 16 + ln];
#pragma unroll
        for (int mt2 = 0; mt2 < 2; ++mt2) {
          acc[mt2][nt] = __builtin_amdgcn_mfma_f32_16x16x32_bf16(
              ah[kc & 1][mt2], bb.s, acc[mt2][nt], 0, 0, 0);
          acc[mt2][nt] = __builtin_amdgcn_mfma_f32_16x16x32_bf16(
              al[kc & 1][mt2], bb.s, acc[mt2][nt], 0, 0, 0);
        }
      }
    }

    cwrite_stats(acc, outp, pS, pQ, bx, b, hw0, wave, q, ln);
  }
}

__global__ __launch_bounds__(256) void gemm1_dual(
    const unsigned short* __restrict__ AH1, const unsigned short* __restrict__ AL1,
    const uint32_t* __restrict__ XP, uint32_t* __restrict__ out1,
    float* __restrict__ sv1, float* __restrict__ sq1,
    const unsigned short* __restrict__ AH2, const unsigned short* __restrict__ AL2,
    const uint32_t* __restrict__ FP, uint32_t* __restrict__ out2,
    float* __restrict__ sv2, float* __restrict__ sq2) {
  __shared__ uint32_t Bs[2 * 64 * KP];
  const int p = blockIdx.x & 511;
  if (blockIdx.x < 512)
    gemm1_persist<T1>(AH1, AL1, XP, out1, sv1, sq1, p, Bs);
  else
    gemm1_persist<T1>(AH2, AL2, FP, out2, sv2, sq2, p, Bs);
}

// --------------------------- gemm2 persistent (K=256) ------------------------
// Per tile: 2 stages (B0 rows then B1 rows), each: stage 64-row half-tile ->
// barrier -> reload ld (next half-tile / next tile) -> 4 k-chunks MFMA.
// Stage parity: buf0 = stage0, buf1 = stage1.
template <int T>
__device__ __forceinline__ void gemm2_persist(
    const unsigned short* __restrict__ AH, const unsigned short* __restrict__ AL,
    const uint32_t* __restrict__ B0, const uint32_t* __restrict__ B1,
    uint32_t* __restrict__ outp, float* __restrict__ pS,
    float* __restrict__ pQ, const int p, uint32_t* Bs) {
  const int tid = threadIdx.x;
  const int lane = tid & 63;
  const int wave = tid >> 6;
  const int sk2 = tid >> 4;
  const int sn4 = (tid & 15) << 2;
  const int q = lane >> 4;
  const int ln = lane & 15;

  uint4 ld[4];
  {
    const int bx0 = p * T;
    const int b = bx0 >> 6, hw0 = (bx0 & 63) << 6;
#pragma unroll
    for (int c = 0; c < 4; ++c)
      ld[c] = *(const uint4*)&B0[((size_t)(b * 64 + c * 16 + sk2)) * 4096 +
                                 hw0 + sn4];
  }

#pragma unroll
  for (int t = 0; t < T; ++t) {
    const int bx = p * T + t;
    const int b = bx >> 6, hw0 = (bx & 63) << 6;

    f32x4 acc[2][4];
#pragma unroll
    for (int i = 0; i < 2; ++i)
#pragma unroll
      for (int j = 0; j < 4; ++j) acc[i][j] = (f32x4)(0.0f);

    s16x8 ah[2][2], al[2][2];

    // ---- stage 0: k-chunks 0..3 from B0 ----
    {
      uint32_t* buf = Bs;
#pragma unroll
      for (int c = 0; c < 4; ++c)
        *(uint4*)&buf[(c * 16 + sk2) * KP + sn4] = ld[c];
#pragma unroll
      for (int mt2 = 0; mt2 < 2; ++mt2) {
        const size_t off = ((size_t)((wave * 2 + mt2) * 64 + lane)) << 3;
        ah[0][mt2] = *(const s16x8*)(AH + off);
        al[0][mt2] = *(const s16x8*)(AL + off);
      }
      __syncthreads();
      // reload: this tile's B1 half (k-chunks 4..7)
#pragma unroll
      for (int c = 0; c < 4; ++c)
        ld[c] = *(const uint4*)&B1[((size_t)(b * 64 + c * 16 + sk2)) * 4096 +
                                   hw0 + sn4];
#pragma unroll
      for (int kc = 0; kc < 4; ++kc) {
        if (kc < 3) {
#pragma unroll
          for (int mt2 = 0; mt2 < 2; ++mt2) {
            const size_t off =
                ((size_t)(((kc + 1) * 8 + wave * 2 + mt2) * 64 + lane)) << 3;
            ah[(kc + 1) & 1][mt2] = *(const s16x8*)(AH + off);
            al[(kc + 1) & 1][mt2] = *(const s16x8*)(AL + off);
          }
        }
#pragma unroll
        for (int nt = 0; nt < 4; ++nt) {
          union { uint32_t u[4]; s16x8 s; } bb;
#pragma unroll
          for (int j = 0; j < 4; ++j)
            bb.u[j] = buf[(kc * 16 + q * 4 + j) * KP + nt * 16 + ln];
#pragma unroll
          for (int mt2 = 0; mt2 < 2; ++mt2) {
            acc[mt2][nt] = __builtin_amdgcn_mfma_f32_16x16x32_bf16(
                ah[kc & 1][mt2], bb.s, acc[mt2][nt], 0, 0, 0);
            acc[mt2][nt] = __builtin_amdgcn_mfma_f32_16x16x32_bf16(
                al[kc & 1][mt2], bb.s, acc[mt2][nt], 0, 0, 0);
          }
        }
      }
    }

    // ---- stage 1: k-chunks 4..7 from B1 ----
    {
      uint32_t* buf = Bs + 64 * KP;
#pragma unroll
      for (int c = 0; c < 4; ++c)
        *(uint4*)&buf[(c * 16 + sk2) * KP + sn4] = ld[c];
#pragma unroll
      for (int mt2 = 0; mt2 < 2; ++mt2) {
        const size_t off =
            ((size_t)((4 * 8 + wave * 2 + mt2) * 64 + lane)) << 3;
        ah[0][mt2] = *(const s16x8*)(AH + off);
        al[0][mt2] = *(const s16x8*)(AL + off);
      }
      __syncthreads();
      if (t + 1 < T) {
        const int bn = bx + 1;
        const int b2 = bn >> 6, hw2 = (bn & 63) << 6;
#pragma unroll
        for (int c = 0; c < 4; ++c)
          ld[c] = *(const uint4*)&B0[((size_t)(b2 * 64 + c * 16 + sk2)) * 4096 +
                                     hw2 + sn4];
      }
#pragma unroll
      for (int kc = 4; kc < 8; ++kc) {
        if (kc < 7) {
#pragma unroll
          for (int mt2 = 0; mt2 < 2; ++mt2) {
            const size_t off =
                ((size_t)(((kc + 1) * 8 + wave * 2 + mt2) * 64 + lane)) << 3;
            ah[(kc + 1) & 1][mt2] = *(const s16x8*)(AH + off);
            al[(kc + 1) & 1][mt2] = *(const s16x8*)(AL + off);
          }
        }
#pragma unroll
        for (int nt = 0; nt < 4; ++nt) {
          union { uint32_t u[4]; s16x8 s; } bb;
#pragma unroll
          for (int j = 0; j < 4; ++j)
            bb.u[j] = buf[((kc - 4) * 16 + q * 4 + j) * KP + nt * 16 + ln];
#pragma unroll
          for (int mt2 = 0; mt2 < 2; ++mt2) {
            acc[mt2][nt] = __builtin_amdgcn_mfma_f32_16x16x32_bf16(
                ah[kc & 1][mt2], bb.s, acc[mt2][nt], 0, 0, 0);
            acc[mt2][nt] = __builtin_amdgcn_mfma_f32_16x16x32_bf16(
                al[kc & 1][mt2], bb.s, acc[mt2][nt], 0, 0, 0);
          }
        }
      }
    }

    cwrite_stats(acc, outp, pS, pQ, bx, b, hw0, wave, q, ln);
  }
}

__global__ __launch_bounds__(256) void gemm2_kernel(
    const unsigned short* __restrict__ AH, const unsigned short* __restrict__ AL,
    const uint32_t* __restrict__ B0, const uint32_t* __restrict__ B1,
    uint32_t* __restrict__ outp, float* __restrict__ sv,
    float* __restrict__ sq) {
  __shared__ uint32_t Bs[2 * 64 * KP];
  gemm2_persist<T2>(AH, AL, B0, B1, outp, sv, sq, blockIdx.x, Bs);
}

// --------------------------- stats reduce -----------------------------------
// P: [nArrays][2048][128] per-tile partials -> p2: [nArrays][16][128].
__global__ __launch_bounds__(256) void reduce_kernel(
    const float* __restrict__ P, float* __restrict__ p2) {
  const int a = blockIdx.x >> 4, g = blockIdx.x & 15;
  const int c = threadIdx.x & 127, h = threadIdx.x >> 7;
  const float* src = P + ((size_t)(a * 2048 + g * 128 + h * 64)) * 128 + c;
  float s0 = 0.f, s1 = 0.f, s2 = 0.f, s3 = 0.f;
#pragma unroll
  for (int j = 0; j < 64; j += 4) {
    s0 += src[(j + 0) * 128];
    s1 += src[(j + 1) * 128];
    s2 += src[(j + 2) * 128];
    s3 += src[(j + 3) * 128];
  }
  __shared__ float sm[256];
  sm[threadIdx.x] = (s0 + s1) + (s2 + s3);
  __syncthreads();
  if (h == 0) p2[(a * 16 + g) * 128 + c] = sm[c] + sm[128 + c];
}

// --------------------------- finalize kernels -------------------------------
__global__ __launch_bounds__(256) void finalize1_kernel(
    const float* __restrict__ p2, const float* __restrict__ g_ibn,
    const float* __restrict__ be_ibn, const float* __restrict__ g_bn,
    const float* __restrict__ w_mr, float* __restrict__ a_in,
    float* __restrict__ d_in, unsigned short* __restrict__ wEffH,
    unsigned short* __restrict__ wEffL) {
  __shared__ float sa[256];
  const int t = threadIdx.x;
  if (t < 128) {
    float s = 0.f, qq = 0.f;
#pragma unroll
    for (int g = 0; g < 16; ++g) {
      s += p2[g * 128 + t];
      qq += p2[(16 + g) * 128 + t];
    }
    const float mu = s * INV_NPIX;
    const float var = fmaxf(qq * INV_NPIX - mu * mu, 0.f);
    const float a = g_ibn[t] * rsqrtf(var + EPS);
    if (blockIdx.x == 0) {
      a_in[t] = a;
      d_in[t] = be_ibn[t] - mu * a;
    }
    sa[t] = a;
  } else {
    const int c = t - 128;
    float s = 0.f, qq = 0.f;
#pragma unroll
    for (int g = 0; g < 16; ++g) {
      s += p2[(32 + g) * 128 + c];
      qq += p2[(48 + g) * 128 + c];
    }
    const float mu = s * INV_NPIX;
    const float var = fmaxf(qq * INV_NPIX - mu * mu, 0.f);
    sa[t] = g_bn[c] * rsqrtf(var + EPS);
  }
  __syncthreads();
  const int e = blockIdx.x * 256 + t;
  const int j = e & 7, l = (e >> 3) & 63, mt = (e >> 9) & 7, kc = e >> 12;
  const int m = mt * 16 + (l & 15);
  const int k = kc * 32 + ((l >> 4) << 3) + j;
  const uint32_t p = pack_hl(w_mr[m * 256 + k] * sa[k]);
  wEffH[e] = (unsigned short)(p & 0xffffu);
  wEffL[e] = (unsigned short)(p >> 16);
}

__global__ __launch_bounds__(128) void finalize2_kernel(
    const float* __restrict__ p2h, const float* __restrict__ g_mbn,
    const float* __restrict__ be_mbn, float* __restrict__ a_m,
    float* __restrict__ d_m) {
  const int t = threadIdx.x;
  float s = 0.f, qq = 0.f;
#pragma unroll
  for (int g = 0; g < 16; ++g) {
    s += p2h[g * 128 + t];
    qq += p2h[(16 + g) * 128 + t];
  }
  const float mu = s * INV_NPIX;
  const float var = fmaxf(qq * INV_NPIX - mu * mu, 0.f);
  const float a = g_mbn[t] * rsqrtf(var + EPS);
  a_m[t] = a;
  d_m[t] = be_mbn[t] - mu * a;
}

// --------------------------- epilogue ---------------------------------------
__device__ __forceinline__ float gelu_exact(float z) {
  return 0.5f * z * (1.0f + erff(z * 0.70710678118654752f));
}

__global__ __launch_bounds__(256) void epilogue_kernel(
    const uint32_t* __restrict__ yp, const uint32_t* __restrict__ hp,
    const float* __restrict__ a_in, const float* __restrict__ d_in,
    const float* __restrict__ a_m, const float* __restrict__ d_m,
    float* __restrict__ out) {
  const size_t i = (size_t)blockIdx.x * 256 + threadIdx.x;  // uint4 index
  const int cp = (int)((i >> 10) & 63);
  const int b = (int)(i >> 16);
  const int c0 = 2 * cp, c1 = 2 * cp + 1;
  const uint4 yv = ((const uint4*)yp)[i];
  const uint4 hv = ((const uint4*)hp)[i];
  const float a0 = a_in[c0], d0 = d_in[c0], m0 = a_m[c0], e0 = d_m[c0];
  const float a1 = a_in[c1], d1 = d_in[c1], m1 = a_m[c1], e1 = d_m[c1];
  float4 o0, o1;
  o0.x = fmaf(a0, bf_lo(yv.x), d0) + gelu_exact(fmaf(m0, bf_lo(hv.x), e0));
  o0.y = fmaf(a0, bf_lo(yv.y), d0) + gelu_exact(fmaf(m0, bf_lo(hv.y), e0));
  o0.z = fmaf(a0, bf_lo(yv.z), d0) + gelu_exact(fmaf(m0, bf_lo(hv.z), e0));
  o0.w = fmaf(a0, bf_lo(yv.w), d0) + gelu_exact(fmaf(m0, bf_lo(hv.w), e0));
  o1.x = fmaf(a1, bf_hi(yv.x), d1) + gelu_exact(fmaf(m1, bf_hi(hv.x), e1));
  o1.y = fmaf(a1, bf_hi(yv.y), d1) + gelu_exact(fmaf(m1, bf_hi(hv.y), e1));
  o1.z = fmaf(a1, bf_hi(yv.z), d1) + gelu_exact(fmaf(m1, bf_hi(hv.z), e1));
  o1.w = fmaf(a1, bf_hi(yv.w), d1) + gelu_exact(fmaf(m1, bf_hi(hv.w), e1));
  const size_t u = i & 1023;  // float4 col within row
  ((float4*)out)[(size_t)(b * 128 + c0) * 1024 + u] = o0;
  ((float4*)out)[(size_t)(b * 128 + c1) * 1024 + u] = o1;
}

// --------------------------- launch -----------------------------------------
extern "C" void kernel_launch(void* const* d_in, const int* in_sizes, int n_in,
                              void* d_out, int out_size, void* d_ws,
                              size_t ws_size, hipStream_t stream) {
  const float* x = (const float*)d_in[0];
  const float* w_diff = (const float*)d_in[1];
  const float* g_bn = (const float*)d_in[3];
  const float* w_in = (const float*)d_in[5];
  const float* g_ibn = (const float*)d_in[7];
  const float* be_ibn = (const float*)d_in[8];
  const float* w_mr = (const float*)d_in[9];
  const float* g_mbn = (const float*)d_in[11];
  const float* be_mbn = (const float*)d_in[12];
  float* out = (float*)d_out;

  const size_t PD = (size_t)8388608;  // 32*64*4096 pair-dwords per tensor
  uint32_t* ws = (uint32_t*)d_ws;
  uint32_t* xp = ws;             // x bf16-pairs
  uint32_t* fpx = ws + PD;       // fmax bf16-pairs
  uint32_t* ypIn = ws + 2 * PD;  // y_in pairs
  uint32_t* ypDf = ws + 3 * PD;  // y_df pairs
  uint32_t* hp = ws + 4 * PD;    // h pairs
  float* st = (float*)(ws + 5 * PD);
  float* p2 = st;               // [4][16][128]
  float* p2h = st + 8192;       // [2][16][128]
  float* a_in = st + 12288, *dinc = st + 12416;
  float* a_m = st + 12544, *d_m = st + 12672;
  unsigned short* fr = (unsigned short*)(st + 12800);
  unsigned short* wInH = fr;           // 16384 each
  unsigned short* wInL = fr + 16384;
  unsigned short* wDfH = fr + 32768;
  unsigned short* wDfL = fr + 49152;
  unsigned short* wEffH = fr + 65536;  // 32768 each
  unsigned short* wEffL = fr + 98304;
  // gemm1 per-tile partials live in the (not-yet-written) hp region;
  // consumed by reduce before gemm2 overwrites hp.
  float* g1p = (float*)(ws + 4 * PD);
  // gemm2 per-tile partials live in the (already-consumed) xp region:
  float* g2p = (float*)ws;

  stencil_prep_kernel<<<2176, 256, 0, stream>>>(x, xp, fpx, w_in, w_diff,
                                                wInH, wInL, wDfH, wDfL);
  gemm1_dual<<<1024, 256, 0, stream>>>(wInH, wInL, xp, ypIn, g1p,
                                       g1p + 262144, wDfH, wDfL, fpx, ypDf,
                                       g1p + 524288, g1p + 786432);
  reduce_kernel<<<64, 256, 0, stream>>>(g1p, p2);
  finalize1_kernel<<<128, 256, 0, stream>>>(p2, g_ibn, be_ibn, g_bn, w_mr,
                                            a_in, dinc, wEffH, wEffL);
  gemm2_kernel<<<1024, 256, 0, stream>>>(wEffH, wEffL, ypIn, ypDf, hp, g2p,
                                         g2p + 262144);
  reduce_kernel<<<32, 256, 0, stream>>>(g2p, p2h);
  finalize2_kernel<<<1, 128, 0, stream>>>(p2h, g_mbn, be_mbn, a_m, d_m);
  epilogue_kernel<<<8192, 256, 0, stream>>>(ypIn, hp, a_in, dinc, a_m, d_m,
                                            out);
}

// Round 6
// 241.789 us; speedup vs baseline: 1.1567x; 1.0482x over previous
//
#include <hip/hip_runtime.h>
#include <math.h>

// ---------------------------------------------------------------------------
// LSGC: B=32, C=128, H=W=64. N_pixels = 32*64*64 = 131072.
// All intermediates stored as bf16 "k-pair" dwords: d = bf16[2c] | bf16[2c+1]<<16,
// layout [b][c/2][hw] — exactly MFMA B-frag pair order.
//   1) stencil: fmax = x - min(...); emits x-pairs and fmax-pairs (+w prep)
//   2) gemm1 dual (persistent, 4 tiles/block): y_in = w_in @ x ; y_df = w_diff @ fmax
//   3) reduce + finalize1: BN scales; w_eff = w_mr * col-scale
//   4) gemm2 (persistent, 2 tiles/block): h = w_eff @ [y_in ; y_df]
//   5) reduce2 ; 6) epilogue (folds finalize2): out = a_in*y + d + gelu(a_m*h + d_m)
// GEMM staging: __builtin_amdgcn_global_load_lds width-16 into LINEAR LDS with
// an XOR bank swizzle folded into the per-lane GLOBAL source address
// (col ^= ((row>>2)&3)<<4) and the same XOR on ds_read -> 2-way (free) banks,
// no VGPR round-trip, no ds_write conflicts. One barrier per 16KB stage; the
// stage for buffer X is issued right after the barrier that frees X, so its
// latency hides under a full stage of MFMA. C-write of tile t is DEFERRED to
// after barrier(t+1): stores drain during tile t+1's compute, not at the
// barrier. Persistent blocks (4/CU resident) keep L2 lines until fully dirty
// (r5: this removed the 1.9x write amplification). Stats non-atomic partials.
// A-side (weights) hi/lo split (2 mfma: ah*b + al*b) for fp32-grade w.
// ---------------------------------------------------------------------------

#define INV_NPIX (1.0f / 131072.0f)
#define EPS 1e-5f
#define T1 4  // tiles per block, gemm1
#define T2 2  // tiles per block, gemm2

typedef __attribute__((ext_vector_type(8))) short s16x8;
typedef __attribute__((ext_vector_type(4))) float f32x4;

__device__ __forceinline__ uint32_t bf16_rne(float v) {
  uint32_t x = __float_as_uint(v);
  return (x + 0x7fffu + ((x >> 16) & 1u)) >> 16;
}
__device__ __forceinline__ uint32_t pack_hl(float v) {
  uint32_t h = bf16_rne(v);
  float lo = v - __uint_as_float(h << 16);
  return h | (bf16_rne(lo) << 16);
}
__device__ __forceinline__ float bf_lo(uint32_t d) {
  return __uint_as_float(d << 16);
}
__device__ __forceinline__ float bf_hi(uint32_t d) {
  return __uint_as_float(d & 0xffff0000u);
}
__device__ __forceinline__ float4 fmin4(float4 a, float4 b) {
  return make_float4(fminf(a.x, b.x), fminf(a.y, b.y), fminf(a.z, b.z),
                     fminf(a.w, b.w));
}

// ------------- stencil (2 planes/block) + pair-pack + prep ------------------
__global__ __launch_bounds__(256) void stencil_prep_kernel(
    const float* __restrict__ x, uint32_t* __restrict__ xp,
    uint32_t* __restrict__ fp, const float* __restrict__ w_in,
    const float* __restrict__ w_diff, unsigned short* __restrict__ wInH,
    unsigned short* __restrict__ wInL, unsigned short* __restrict__ wDfH,
    unsigned short* __restrict__ wDfL) {
  __shared__ float4 pA[1024];
  __shared__ float4 pB[1024];
  if (blockIdx.x >= 2048) {
    const int t = (blockIdx.x - 2048) * 256 + threadIdx.x;  // 0..32767
    const int e = t & 16383;
    const float* w = (t < 16384) ? w_in : w_diff;
    unsigned short* aH = (t < 16384) ? wInH : wDfH;
    unsigned short* aL = (t < 16384) ? wInL : wDfL;
    const int j = e & 7, l = (e >> 3) & 63, mt = (e >> 9) & 7, kc = e >> 12;
    const int m = mt * 16 + (l & 15);
    const int k = kc * 32 + ((l >> 4) << 3) + j;
    const uint32_t p = pack_hl(w[m * 128 + k]);
    aH[e] = (unsigned short)(p & 0xffffu);
    aL[e] = (unsigned short)(p >> 16);
    return;
  }
  const int b = blockIdx.x >> 6;
  const int cp = blockIdx.x & 63;
  const float4* xa = (const float4*)x + (size_t)(b * 128 + 2 * cp) * 1024;
  const float4* xb = xa + 1024;
  float4 sA[4], sB[4];
#pragma unroll
  for (int i = 0; i < 4; ++i) {
    const int u = threadIdx.x + i * 256;
    sA[i] = xa[u];
    sB[i] = xb[u];
    pA[u] = sA[i];
    pB[u] = sB[i];
  }
  __syncthreads();
  const size_t obase = (size_t)(b * 64 + cp) * 1024;  // uint4 units
#pragma unroll
  for (int i = 0; i < 4; ++i) {
    const int u = threadIdx.x + i * 256;
    const int h = u >> 4, wu = u & 15;
    const int row = u & ~15;
    float4 mA, mB;
    {
      const float4 A = sA[i];
      const float4 L = pA[row | ((wu + 15) & 15)];
      const float4 R = pA[row | ((wu + 1) & 15)];
      float4 m = fmin4(A, fmin4(L, R));
      m = fmin4(m, make_float4(A.z, A.w, R.x, R.y));
      m = fmin4(m, make_float4(L.z, L.w, A.x, A.y));
      m = fmin4(m, pA[row | ((wu + 2) & 15)]);
      m = fmin4(m, pA[row | ((wu + 14) & 15)]);
      m = fmin4(m, pA[row | ((wu + 4) & 15)]);
      m = fmin4(m, pA[row | ((wu + 12) & 15)]);
      m = fmin4(m, pA[row | ((wu + 8) & 15)]);
      m = fmin4(m, pA[(((h + 2) & 63) << 4) | wu]);
      m = fmin4(m, pA[(((h + 62) & 63) << 4) | wu]);
      m = fmin4(m, pA[(((h + 4) & 63) << 4) | wu]);
      m = fmin4(m, pA[(((h + 60) & 63) << 4) | wu]);
      m = fmin4(m, pA[(((h + 8) & 63) << 4) | wu]);
      m = fmin4(m, pA[(((h + 56) & 63) << 4) | wu]);
      m = fmin4(m, pA[(((h + 16) & 63) << 4) | wu]);
      m = fmin4(m, pA[(((h + 48) & 63) << 4) | wu]);
      m = fmin4(m, pA[(((h + 32) & 63) << 4) | wu]);
      mA = m;
    }
    {
      const float4 A = sB[i];
      const float4 L = pB[row | ((wu + 15) & 15)];
      const float4 R = pB[row | ((wu + 1) & 15)];
      float4 m = fmin4(A, fmin4(L, R));
      m = fmin4(m, make_float4(A.z, A.w, R.x, R.y));
      m = fmin4(m, make_float4(L.z, L.w, A.x, A.y));
      m = fmin4(m, pB[row | ((wu + 2) & 15)]);
      m = fmin4(m, pB[row | ((wu + 14) & 15)]);
      m = fmin4(m, pB[row | ((wu + 4) & 15)]);
      m = fmin4(m, pB[row | ((wu + 12) & 15)]);
      m = fmin4(m, pB[row | ((wu + 8) & 15)]);
      m = fmin4(m, pB[(((h + 2) & 63) << 4) | wu]);
      m = fmin4(m, pB[(((h + 62) & 63) << 4) | wu]);
      m = fmin4(m, pB[(((h + 4) & 63) << 4) | wu]);
      m = fmin4(m, pB[(((h + 60) & 63) << 4) | wu]);
      m = fmin4(m, pB[(((h + 8) & 63) << 4) | wu]);
      m = fmin4(m, pB[(((h + 56) & 63) << 4) | wu]);
      m = fmin4(m, pB[(((h + 16) & 63) << 4) | wu]);
      m = fmin4(m, pB[(((h + 48) & 63) << 4) | wu]);
      m = fmin4(m, pB[(((h + 32) & 63) << 4) | wu]);
      mB = m;
    }
    uint4 px, pf;
    px.x = bf16_rne(sA[i].x) | (bf16_rne(sB[i].x) << 16);
    px.y = bf16_rne(sA[i].y) | (bf16_rne(sB[i].y) << 16);
    px.z = bf16_rne(sA[i].z) | (bf16_rne(sB[i].z) << 16);
    px.w = bf16_rne(sA[i].w) | (bf16_rne(sB[i].w) << 16);
    pf.x = bf16_rne(sA[i].x - mA.x) | (bf16_rne(sB[i].x - mB.x) << 16);
    pf.y = bf16_rne(sA[i].y - mA.y) | (bf16_rne(sB[i].y - mB.y) << 16);
    pf.z = bf16_rne(sA[i].z - mA.z) | (bf16_rne(sB[i].z - mB.z) << 16);
    pf.w = bf16_rne(sA[i].w - mA.w) | (bf16_rne(sB[i].w - mB.w) << 16);
    ((uint4*)xp)[obase + u] = px;
    ((uint4*)fp)[obase + u] = pf;
  }
}

// ------------------ async stage: global -> LDS (swizzled src) ----------------
// Tile = 64 rows x 64 dwords, linear in LDS (4096 dwords). Wave w stages rows
// 16w..16w+15 with 4 gload_lds (1KB each). Source col xored by i<<4 so that
// LDS[row][c] = G[row][c ^ (((row>>2)&3)<<4)] — read side applies same XOR.
__device__ __forceinline__ void stage_tile(const uint32_t* __restrict__ B,
                                           const int b, const int hw0,
                                           uint32_t* lbuf, const int wave,
                                           const int lane) {
  const int qq = lane >> 4, ln = lane & 15;
#pragma unroll
  for (int i = 0; i < 4; ++i) {
    const int row = wave * 16 + i * 4 + qq;
    const uint32_t* src =
        &B[((size_t)(b * 64 + row)) * 4096 + hw0 + ((ln * 4) ^ (i << 4))];
    uint32_t* dst = lbuf + (wave * 16 + i * 4) * 64;  // wave-uniform base
    __builtin_amdgcn_global_load_lds(
        (const __attribute__((address_space(1))) void*)src,
        (__attribute__((address_space(3))) void*)dst, 16, 0, 0);
  }
}

// --------------------------- C-write + stats ---------------------------------
__device__ __forceinline__ void cwrite_stats(
    const f32x4 (&acc)[2][4], uint32_t* __restrict__ outp,
    float* __restrict__ pS, float* __restrict__ pQ, const int bx,
    const int wave, const int q, const int ln) {
  const int b = bx >> 6, hw0 = (bx & 63) << 6;
#pragma unroll
  for (int mt2 = 0; mt2 < 2; ++mt2) {
    float sa[4] = {0.f, 0.f, 0.f, 0.f};
    float sq[4] = {0.f, 0.f, 0.f, 0.f};
#pragma unroll
    for (int nt = 0; nt < 4; ++nt) {
#pragma unroll
      for (int rp = 0; rp < 2; ++rp) {
        const float v0 = acc[mt2][nt][2 * rp];
        const float v1 = acc[mt2][nt][2 * rp + 1];
        const int m2 = (wave * 2 + mt2) * 8 + q * 2 + rp;
        outp[((size_t)(b * 64 + m2)) * 4096 + hw0 + nt * 16 + ln] =
            bf16_rne(v0) | (bf16_rne(v1) << 16);
        sa[2 * rp] += v0;
        sq[2 * rp] += v0 * v0;
        sa[2 * rp + 1] += v1;
        sq[2 * rp + 1] += v1 * v1;
      }
    }
#pragma unroll
    for (int off = 1; off < 16; off <<= 1) {
#pragma unroll
      for (int r = 0; r < 4; ++r) {
        sa[r] += __shfl_xor(sa[r], off);
        sq[r] += __shfl_xor(sq[r], off);
      }
    }
    if (ln == 0) {
#pragma unroll
      for (int r = 0; r < 4; ++r) {
        const int m = (wave * 2 + mt2) * 16 + q * 4 + r;
        pS[bx * 128 + m] = sa[r];
        pQ[bx * 128 + m] = sq[r];
      }
    }
  }
}

// --------------------------- gemm1 persistent (K=128) ------------------------
template <int T>
__device__ __forceinline__ void gemm1_persist(
    const unsigned short* __restrict__ AH, const unsigned short* __restrict__ AL,
    const uint32_t* __restrict__ B0, uint32_t* __restrict__ outp,
    float* __restrict__ pS, float* __restrict__ pQ, const int p,
    uint32_t* Bs) {
  const int tid = threadIdx.x;
  const int lane = tid & 63;
  const int wave = tid >> 6;
  const int q = lane >> 4;
  const int ln = lane & 15;

  stage_tile(B0, (p * T) >> 6, ((p * T) & 63) << 6, Bs, wave, lane);

  f32x4 accA[2][4], accB[2][4];

#pragma unroll
  for (int t = 0; t < T; ++t) {
    const int bx = p * T + t;
    uint32_t* buf = Bs + (t & 1) * 4096;
    __syncthreads();  // drains gloads for buf (+ prev tile's stores)
    if (t + 1 < T) {
      const int bn = bx + 1;
      stage_tile(B0, bn >> 6, (bn & 63) << 6, Bs + ((t + 1) & 1) * 4096, wave,
                 lane);
    }
    s16x8 ah[2][2], al[2][2];
#pragma unroll
    for (int mt2 = 0; mt2 < 2; ++mt2) {
      const size_t off = ((size_t)((wave * 2 + mt2) * 64 + lane)) << 3;
      ah[0][mt2] = *(const s16x8*)(AH + off);
      al[0][mt2] = *(const s16x8*)(AL + off);
    }
    // deferred C-write of previous tile: stores drain during this compute
    if (t > 0)
      cwrite_stats((t & 1) ? accA : accB, outp, pS, pQ, bx - 1, wave, q, ln);
    f32x4(&acc)[2][4] = (t & 1) ? accB : accA;
#pragma unroll
    for (int i = 0; i < 2; ++i)
#pragma unroll
      for (int jj = 0; jj < 4; ++jj) acc[i][jj] = (f32x4)(0.0f);
#pragma unroll
    for (int kc = 0; kc < 4; ++kc) {
      if (kc < 3) {
#pragma unroll
        for (int mt2 = 0; mt2 < 2; ++mt2) {
          const size_t off =
              ((size_t)(((kc + 1) * 8 + wave * 2 + mt2) * 64 + lane)) << 3;
          ah[(kc + 1) & 1][mt2] = *(const s16x8*)(AH + off);
          al[(kc + 1) & 1][mt2] = *(const s16x8*)(AL + off);
        }
      }
#pragma unroll
      for (int nt = 0; nt < 4; ++nt) {
        union { uint32_t u[4]; s16x8 s; } bb;
#pragma unroll
        for (int j = 0; j < 4; ++j)
          bb.u[j] =
              buf[(kc * 16 + q * 4 + j) * 64 + ((nt * 16 + ln) ^ (q << 4))];
#pragma unroll
        for (int mt2 = 0; mt2 < 2; ++mt2) {
          acc[mt2][nt] = __builtin_amdgcn_mfma_f32_16x16x32_bf16(
              ah[kc & 1][mt2], bb.s, acc[mt2][nt], 0, 0, 0);
          acc[mt2][nt] = __builtin_amdgcn_mfma_f32_16x16x32_bf16(
              al[kc & 1][mt2], bb.s, acc[mt2][nt], 0, 0, 0);
        }
      }
    }
  }
  cwrite_stats(((T - 1) & 1) ? accB : accA, outp, pS, pQ, p * T + T - 1, wave,
               q, ln);
}

__global__ __launch_bounds__(256) void gemm1_dual(
    const unsigned short* __restrict__ AH1, const unsigned short* __restrict__ AL1,
    const uint32_t* __restrict__ XP, uint32_t* __restrict__ out1,
    float* __restrict__ sv1, float* __restrict__ sq1,
    const unsigned short* __restrict__ AH2, const unsigned short* __restrict__ AL2,
    const uint32_t* __restrict__ FP, uint32_t* __restrict__ out2,
    float* __restrict__ sv2, float* __restrict__ sq2) {
  __shared__ uint32_t Bs[2 * 4096];
  const int p = blockIdx.x & 511;
  if (blockIdx.x < 512)
    gemm1_persist<T1>(AH1, AL1, XP, out1, sv1, sq1, p, Bs);
  else
    gemm1_persist<T1>(AH2, AL2, FP, out2, sv2, sq2, p, Bs);
}

// --------------------------- gemm2 persistent (K=256) ------------------------
// 2 stages per tile (B0 rows = k-chunks 0..3, B1 rows = 4..7); acc spans both;
// C-write deferred into the next tile's first stage.
template <int T>
__device__ __forceinline__ void gemm2_persist(
    const unsigned short* __restrict__ AH, const unsigned short* __restrict__ AL,
    const uint32_t* __restrict__ B0, const uint32_t* __restrict__ B1,
    uint32_t* __restrict__ outp, float* __restrict__ pS,
    float* __restrict__ pQ, const int p, uint32_t* Bs) {
  const int tid = threadIdx.x;
  const int lane = tid & 63;
  const int wave = tid >> 6;
  const int q = lane >> 4;
  const int ln = lane & 15;

  stage_tile(B0, (p * T) >> 6, ((p * T) & 63) << 6, Bs, wave, lane);

  f32x4 accA[2][4], accB[2][4];

#pragma unroll
  for (int s = 0; s < 2 * T; ++s) {
    const int t = s >> 1, half = s & 1;
    const int bx = p * T + t;
    uint32_t* buf = Bs + (s & 1) * 4096;
    __syncthreads();
    if (s + 1 < 2 * T) {
      const int s2 = s + 1;
      const int bx2 = p * T + (s2 >> 1);
      stage_tile((s2 & 1) ? B1 : B0, bx2 >> 6, (bx2 & 63) << 6,
                 Bs + (s2 & 1) * 4096, wave, lane);
    }
    const int kb = half * 4;  // first global k-chunk of this stage
    s16x8 ah[2][2], al[2][2];
#pragma unroll
    for (int mt2 = 0; mt2 < 2; ++mt2) {
      const size_t off =
          ((size_t)((kb * 8 + wave * 2 + mt2) * 64 + lane)) << 3;
      ah[0][mt2] = *(const s16x8*)(AH + off);
      al[0][mt2] = *(const s16x8*)(AL + off);
    }
    f32x4(&acc)[2][4] = (t & 1) ? accB : accA;
    if (half == 0) {
      if (t > 0)
        cwrite_stats((t & 1) ? accA : accB, outp, pS, pQ, bx - 1, wave, q, ln);
#pragma unroll
      for (int i = 0; i < 2; ++i)
#pragma unroll
        for (int jj = 0; jj < 4; ++jj) acc[i][jj] = (f32x4)(0.0f);
    }
#pragma unroll
    for (int kc = 0; kc < 4; ++kc) {
      if (kc < 3) {
#pragma unroll
        for (int mt2 = 0; mt2 < 2; ++mt2) {
          const size_t off =
              ((size_t)(((kb + kc + 1) * 8 + wave * 2 + mt2) * 64 + lane))
              << 3;
          ah[(kc + 1) & 1][mt2] = *(const s16x8*)(AH + off);
          al[(kc + 1) & 1][mt2] = *(const s16x8*)(AL + off);
        }
      }
#pragma unroll
      for (int nt = 0; nt < 4; ++nt) {
        union { uint32_t u[4]; s16x8 s; } bb;
#pragma unroll
        for (int j = 0; j < 4; ++j)
          bb.u[j] =
              buf[(kc * 16 + q * 4 + j) * 64 + ((nt * 16 + ln) ^ (q << 4))];
#pragma unroll
        for (int mt2 = 0; mt2 < 2; ++mt2) {
          acc[mt2][nt] = __builtin_amdgcn_mfma_f32_16x16x32_bf16(
              ah[kc & 1][mt2], bb.s, acc[mt2][nt], 0, 0, 0);
          acc[mt2][nt] = __builtin_amdgcn_mfma_f32_16x16x32_bf16(
              al[kc & 1][mt2], bb.s, acc[mt2][nt], 0, 0, 0);
        }
      }
    }
  }
  cwrite_stats(((T - 1) & 1) ? accB : accA, outp, pS, pQ, p * T + T - 1, wave,
               q, ln);
}

__global__ __launch_bounds__(256) void gemm2_kernel(
    const unsigned short* __restrict__ AH, const unsigned short* __restrict__ AL,
    const uint32_t* __restrict__ B0, const uint32_t* __restrict__ B1,
    uint32_t* __restrict__ outp, float* __restrict__ sv,
    float* __restrict__ sq) {
  __shared__ uint32_t Bs[2 * 4096];
  gemm2_persist<T2>(AH, AL, B0, B1, outp, sv, sq, blockIdx.x, Bs);
}

// --------------------------- stats reduce -----------------------------------
__global__ __launch_bounds__(256) void reduce_kernel(
    const float* __restrict__ P, float* __restrict__ p2) {
  const int a = blockIdx.x >> 4, g = blockIdx.x & 15;
  const int c = threadIdx.x & 127, h = threadIdx.x >> 7;
  const float* src = P + ((size_t)(a * 2048 + g * 128 + h * 64)) * 128 + c;
  float s0 = 0.f, s1 = 0.f, s2 = 0.f, s3 = 0.f;
#pragma unroll
  for (int j = 0; j < 64; j += 4) {
    s0 += src[(j + 0) * 128];
    s1 += src[(j + 1) * 128];
    s2 += src[(j + 2) * 128];
    s3 += src[(j + 3) * 128];
  }
  __shared__ float sm[256];
  sm[threadIdx.x] = (s0 + s1) + (s2 + s3);
  __syncthreads();
  if (h == 0) p2[(a * 16 + g) * 128 + c] = sm[c] + sm[128 + c];
}

// --------------------------- finalize1 ---------------------------------------
__global__ __launch_bounds__(256) void finalize1_kernel(
    const float* __restrict__ p2, const float* __restrict__ g_ibn,
    const float* __restrict__ be_ibn, const float* __restrict__ g_bn,
    const float* __restrict__ w_mr, float* __restrict__ a_in,
    float* __restrict__ d_in, unsigned short* __restrict__ wEffH,
    unsigned short* __restrict__ wEffL) {
  __shared__ float sa[256];
  const int t = threadIdx.x;
  if (t < 128) {
    float s = 0.f, qq = 0.f;
#pragma unroll
    for (int g = 0; g < 16; ++g) {
      s += p2[g * 128 + t];
      qq += p2[(16 + g) * 128 + t];
    }
    const float mu = s * INV_NPIX;
    const float var = fmaxf(qq * INV_NPIX - mu * mu, 0.f);
    const float a = g_ibn[t] * rsqrtf(var + EPS);
    if (blockIdx.x == 0) {
      a_in[t] = a;
      d_in[t] = be_ibn[t] - mu * a;
    }
    sa[t] = a;
  } else {
    const int c = t - 128;
    float s = 0.f, qq = 0.f;
#pragma unroll
    for (int g = 0; g < 16; ++g) {
      s += p2[(32 + g) * 128 + c];
      qq += p2[(48 + g) * 128 + c];
    }
    const float mu = s * INV_NPIX;
    const float var = fmaxf(qq * INV_NPIX - mu * mu, 0.f);
    sa[t] = g_bn[c] * rsqrtf(var + EPS);
  }
  __syncthreads();
  const int e = blockIdx.x * 256 + t;
  const int j = e & 7, l = (e >> 3) & 63, mt = (e >> 9) & 7, kc = e >> 12;
  const int m = mt * 16 + (l & 15);
  const int k = kc * 32 + ((l >> 4) << 3) + j;
  const uint32_t p = pack_hl(w_mr[m * 256 + k] * sa[k]);
  wEffH[e] = (unsigned short)(p & 0xffffu);
  wEffL[e] = (unsigned short)(p >> 16);
}

// --------------------------- epilogue (folds finalize2) ----------------------
__device__ __forceinline__ float gelu_exact(float z) {
  return 0.5f * z * (1.0f + erff(z * 0.70710678118654752f));
}

__global__ __launch_bounds__(256) void epilogue_kernel(
    const uint32_t* __restrict__ yp, const uint32_t* __restrict__ hp,
    const float* __restrict__ a_in, const float* __restrict__ d_in,
    const float* __restrict__ p2h, const float* __restrict__ g_mbn,
    const float* __restrict__ be_mbn, float* __restrict__ out) {
  __shared__ float sAi[128], sDi[128], sAm[128], sDm[128];
  const int tid = threadIdx.x;
  if (tid < 128) {
    float s = 0.f, qq = 0.f;
#pragma unroll
    for (int g = 0; g < 16; ++g) {
      s += p2h[g * 128 + tid];
      qq += p2h[(16 + g) * 128 + tid];
    }
    const float mu = s * INV_NPIX;
    const float var = fmaxf(qq * INV_NPIX - mu * mu, 0.f);
    const float a = g_mbn[tid] * rsqrtf(var + EPS);
    sAm[tid] = a;
    sDm[tid] = be_mbn[tid] - mu * a;
    sAi[tid] = a_in[tid];
    sDi[tid] = d_in[tid];
  }
  __syncthreads();
#pragma unroll
  for (int it = 0; it < 4; ++it) {
    const size_t i = (size_t)(blockIdx.x * 4 + it) * 256 + tid;  // uint4 idx
    const int cp = (int)((i >> 10) & 63);
    const int b = (int)(i >> 16);
    const int c0 = 2 * cp, c1 = 2 * cp + 1;
    const uint4 yv = ((const uint4*)yp)[i];
    const uint4 hv = ((const uint4*)hp)[i];
    const float a0 = sAi[c0], d0 = sDi[c0], m0 = sAm[c0], e0 = sDm[c0];
    const float a1 = sAi[c1], d1 = sDi[c1], m1 = sAm[c1], e1 = sDm[c1];
    float4 o0, o1;
    o0.x = fmaf(a0, bf_lo(yv.x), d0) + gelu_exact(fmaf(m0, bf_lo(hv.x), e0));
    o0.y = fmaf(a0, bf_lo(yv.y), d0) + gelu_exact(fmaf(m0, bf_lo(hv.y), e0));
    o0.z = fmaf(a0, bf_lo(yv.z), d0) + gelu_exact(fmaf(m0, bf_lo(hv.z), e0));
    o0.w = fmaf(a0, bf_lo(yv.w), d0) + gelu_exact(fmaf(m0, bf_lo(hv.w), e0));
    o1.x = fmaf(a1, bf_hi(yv.x), d1) + gelu_exact(fmaf(m1, bf_hi(hv.x), e1));
    o1.y = fmaf(a1, bf_hi(yv.y), d1) + gelu_exact(fmaf(m1, bf_hi(hv.y), e1));
    o1.z = fmaf(a1, bf_hi(yv.z), d1) + gelu_exact(fmaf(m1, bf_hi(hv.z), e1));
    o1.w = fmaf(a1, bf_hi(yv.w), d1) + gelu_exact(fmaf(m1, bf_hi(hv.w), e1));
    const size_t u = i & 1023;  // float4 col within row
    ((float4*)out)[(size_t)(b * 128 + c0) * 1024 + u] = o0;
    ((float4*)out)[(size_t)(b * 128 + c1) * 1024 + u] = o1;
  }
}

// --------------------------- launch -----------------------------------------
extern "C" void kernel_launch(void* const* d_in, const int* in_sizes, int n_in,
                              void* d_out, int out_size, void* d_ws,
                              size_t ws_size, hipStream_t stream) {
  const float* x = (const float*)d_in[0];
  const float* w_diff = (const float*)d_in[1];
  const float* g_bn = (const float*)d_in[3];
  const float* w_in = (const float*)d_in[5];
  const float* g_ibn = (const float*)d_in[7];
  const float* be_ibn = (const float*)d_in[8];
  const float* w_mr = (const float*)d_in[9];
  const float* g_mbn = (const float*)d_in[11];
  const float* be_mbn = (const float*)d_in[12];
  float* out = (float*)d_out;

  const size_t PD = (size_t)8388608;  // 32*64*4096 pair-dwords per tensor
  uint32_t* ws = (uint32_t*)d_ws;
  uint32_t* xp = ws;             // x bf16-pairs
  uint32_t* fpx = ws + PD;       // fmax bf16-pairs
  uint32_t* ypIn = ws + 2 * PD;  // y_in pairs
  uint32_t* ypDf = ws + 3 * PD;  // y_df pairs
  uint32_t* hp = ws + 4 * PD;    // h pairs
  float* st = (float*)(ws + 5 * PD);
  float* p2 = st;          // [4][16][128]
  float* p2h = st + 8192;  // [2][16][128]
  float* a_in = st + 12288, *dinc = st + 12416;
  unsigned short* fr = (unsigned short*)(st + 12800);
  unsigned short* wInH = fr;  // 16384 each
  unsigned short* wInL = fr + 16384;
  unsigned short* wDfH = fr + 32768;
  unsigned short* wDfL = fr + 49152;
  unsigned short* wEffH = fr + 65536;  // 32768 each
  unsigned short* wEffL = fr + 98304;
  // gemm1 partials in the (not-yet-written) hp region (consumed by reduce1
  // before gemm2 overwrites hp); gemm2 partials in the dead xp region.
  float* g1p = (float*)(ws + 4 * PD);
  float* g2p = (float*)ws;

  stencil_prep_kernel<<<2176, 256, 0, stream>>>(x, xp, fpx, w_in, w_diff,
                                                wInH, wInL, wDfH, wDfL);
  gemm1_dual<<<1024, 256, 0, stream>>>(wInH, wInL, xp, ypIn, g1p,
                                       g1p + 262144, wDfH, wDfL, fpx, ypDf,
                                       g1p + 524288, g1p + 786432);
  reduce_kernel<<<64, 256, 0, stream>>>(g1p, p2);
  finalize1_kernel<<<128, 256, 0, stream>>>(p2, g_ibn, be_ibn, g_bn, w_mr,
                                            a_in, dinc, wEffH, wEffL);
  gemm2_kernel<<<1024, 256, 0, stream>>>(wEffH, wEffL, ypIn, ypDf, hp, g2p,
                                         g2p + 262144);
  reduce_kernel<<<32, 256, 0, stream>>>(g2p, p2h);
  epilogue_kernel<<<2048, 256, 0, stream>>>(ypIn, hp, a_in, dinc, p2h, g_mbn,
                                            be_mbn, out);
}